// Round 1
// baseline (960.245 us; speedup 1.0000x reference)
//
#include <hip/hip_runtime.h>

typedef unsigned short ushort_t;
typedef __attribute__((ext_vector_type(8))) short short8;
typedef __attribute__((ext_vector_type(8))) unsigned short ushort8;
typedef __attribute__((ext_vector_type(4))) float floatx4;

#define M_TOT 32768   // B*S
#define KDIM  1024    // folded reduction dim (x part only)
#define N3    6144    // 3 * 2048 (q,k,v outputs)
#define D2    2048
#define NBATCH 1024
#define SSEQ   32

__device__ __forceinline__ ushort_t f2bf(float f){
  unsigned int u = __builtin_bit_cast(unsigned int, f);
  u += 0x7fffu + ((u >> 16) & 1u);           // RNE
  return (ushort_t)(u >> 16);
}

__device__ __forceinline__ void gld16(const void* g, void* l){
  __builtin_amdgcn_global_load_lds((__attribute__((address_space(1))) void*)g,
                                   (__attribute__((address_space(3))) void*)l,
                                   16, 0, 0);
}

// ---------------- prep kernels ----------------

__global__ void k_cast_x(const float* __restrict__ x, ushort_t* __restrict__ xb){
  size_t i = (size_t)blockIdx.x * 256 + threadIdx.x;   // one thread per 8 elems
  const float4* s = (const float4*)x;
  float4 a = s[2*i], b = s[2*i+1];
  ushort8 o;
  o[0]=f2bf(a.x); o[1]=f2bf(a.y); o[2]=f2bf(a.z); o[3]=f2bf(a.w);
  o[4]=f2bf(b.x); o[5]=f2bf(b.y); o[6]=f2bf(b.z); o[7]=f2bf(b.w);
  *(ushort8*)(xb + 8*i) = o;
}

// W_all[row=p*2048+n][j] = W_p[n][j] for j<1024  (left half of each weight row)
__global__ void k_cast_w(const float* __restrict__ Wq, const float* __restrict__ Wk,
                         const float* __restrict__ Wv, ushort_t* __restrict__ Wall){
  int i = blockIdx.x * 256 + threadIdx.x;
  int e = i * 8;
  int row = e >> 10, col = e & 1023;
  int p = row >> 11, n = row & 2047;
  const float* W = (p==0) ? Wq : (p==1) ? Wk : Wv;
  const float4* s = (const float4*)(W + (size_t)n*2048 + col);
  float4 a = s[0], b = s[1];
  ushort8 o;
  o[0]=f2bf(a.x); o[1]=f2bf(a.y); o[2]=f2bf(a.z); o[3]=f2bf(a.w);
  o[4]=f2bf(b.x); o[5]=f2bf(b.y); o[6]=f2bf(b.z); o[7]=f2bf(b.w);
  *(ushort8*)(Wall + (size_t)row*1024 + col) = o;
}

__global__ void k_cast_wfc(const float* __restrict__ Wfc, ushort_t* __restrict__ wfcb){
  int i = blockIdx.x * 256 + threadIdx.x;
  const float4* s = (const float4*)Wfc;
  float4 a = s[2*i], b = s[2*i+1];
  ushort8 o;
  o[0]=f2bf(a.x); o[1]=f2bf(a.y); o[2]=f2bf(a.z); o[3]=f2bf(a.w);
  o[4]=f2bf(b.x); o[5]=f2bf(b.y); o[6]=f2bf(b.z); o[7]=f2bf(b.w);
  *(ushort8*)(wfcb + 8*(size_t)i) = o;
}

// bias_all[s][p*2048+n] = b_p[n] + sum_j pe[s][j] * W_p[n][1024+j]   (fp32)
__global__ void k_bias(const float* __restrict__ pe,
                       const float* __restrict__ Wq, const float* __restrict__ bq,
                       const float* __restrict__ Wk, const float* __restrict__ bk,
                       const float* __restrict__ Wv, const float* __restrict__ bv,
                       float* __restrict__ bias_all){
  int t = threadIdx.x;
  int ni = t & 7, s = t >> 3;
  int col = blockIdx.x * 8 + ni;           // 0..6143
  int p = col >> 11, n = col & 2047;
  const float* W  = (p==0) ? Wq : (p==1) ? Wk : Wv;
  const float* bb = (p==0) ? bq : (p==1) ? bk : bv;
  const float4* w4 = (const float4*)(W + (size_t)n*2048 + 1024);
  const float4* p4 = (const float4*)(pe + (size_t)s*1024);
  float acc = 0.f;
  #pragma unroll 4
  for (int j = 0; j < 256; ++j){
    float4 w = w4[j], q = p4[j];
    acc += w.x*q.x + w.y*q.y + w.z*q.z + w.w*q.w;
  }
  bias_all[(size_t)s*N3 + col] = acc + bb[n];
}

// ---------------- QKV GEMM: qkv[m][n] = sum_k xb[m][k]*Wall[n][k] + bias_all[m%32][n] ----------------
// 128x128 tile, BK=32, 4 waves (2x2), 16x16x32 bf16 MFMA, 4x4 frags/wave (m97 structure)
__global__ __launch_bounds__(256) void k_gemm(const ushort_t* __restrict__ xb,
                                              const ushort_t* __restrict__ Wall,
                                              const float* __restrict__ bias_all,
                                              ushort_t* __restrict__ qkv){
  __shared__ alignas(16) ushort_t As[128*32];
  __shared__ alignas(16) ushort_t Bs[128*32];
  const int m0 = blockIdx.x * 128;
  const int n0 = blockIdx.y * 128;
  const int t = threadIdx.x, w = t >> 6, l = t & 63;
  const int wr = w >> 1, wc = w & 1;
  const int lr = l & 15, lg = l >> 4;

  floatx4 acc[4][4] = {};

  // staging chunks: 512 x 16B per operand; thread does chunks c0 (j=0) and c1 (j=1)
  const int c0 = w*64 + l, c1 = 256 + c0;
  const int r0 = c0 >> 2, e0 = (c0 & 3) * 8;
  const int r1 = c1 >> 2, e1 = (c1 & 3) * 8;
  const ushort_t* a0 = xb + (size_t)(m0 + r0)*KDIM + e0;
  const ushort_t* a1 = xb + (size_t)(m0 + r1)*KDIM + e1;
  const ushort_t* b0 = Wall + (size_t)(n0 + r0)*KDIM + e0;
  const ushort_t* b1 = Wall + (size_t)(n0 + r1)*KDIM + e1;
  ushort_t* lA0 = As + (size_t)(w*64)*8;        // wave-uniform bases (HW adds lane*16B)
  ushort_t* lA1 = As + (size_t)(256 + w*64)*8;
  ushort_t* lB0 = Bs + (size_t)(w*64)*8;
  ushort_t* lB1 = Bs + (size_t)(256 + w*64)*8;

  for (int k0 = 0; k0 < KDIM; k0 += 32){
    gld16(a0 + k0, lA0);
    gld16(a1 + k0, lA1);
    gld16(b0 + k0, lB0);
    gld16(b1 + k0, lB1);
    __syncthreads();
    short8 af[4], bfr[4];
    #pragma unroll
    for (int m = 0; m < 4; ++m)
      af[m] = *(const short8*)(As + (wr*64 + m*16 + lr)*32 + lg*8);
    #pragma unroll
    for (int n = 0; n < 4; ++n)
      bfr[n] = *(const short8*)(Bs + (wc*64 + n*16 + lr)*32 + lg*8);
    #pragma unroll
    for (int m = 0; m < 4; ++m)
      #pragma unroll
      for (int n = 0; n < 4; ++n)
        acc[m][n] = __builtin_amdgcn_mfma_f32_16x16x32_bf16(af[m], bfr[n], acc[m][n], 0, 0, 0);
    __syncthreads();
  }

  // epilogue: C/D layout col=l&15, row=(l>>4)*4+reg
  #pragma unroll
  for (int m = 0; m < 4; ++m){
    #pragma unroll
    for (int n = 0; n < 4; ++n){
      #pragma unroll
      for (int r = 0; r < 4; ++r){
        int row = m0 + wr*64 + m*16 + lg*4 + r;
        int col = n0 + wc*64 + n*16 + lr;
        float v = acc[m][n][r] + bias_all[(size_t)(row & 31)*N3 + col];
        qkv[(size_t)row*N3 + col] = f2bf(v);
      }
    }
  }
}

// ---------------- logits[b][qi][ki] = (1/sqrt(2048)) * sum_d q[qi,d]*k[ki,d] ----------------
__global__ __launch_bounds__(256) void k_logits(const ushort_t* __restrict__ qkv,
                                                float* __restrict__ logits){
  __shared__ alignas(16) ushort_t qs[32*128];
  __shared__ alignas(16) ushort_t ks[32*128];
  const int b = blockIdx.x;
  const int t = threadIdx.x, w = t >> 6, l = t & 63;
  const int qh = w >> 1, kh = w & 1;
  const int lr = l & 15, lg = l >> 4;
  floatx4 acc = {0.f, 0.f, 0.f, 0.f};

  const int c0 = w*64 + l, c1 = 256 + c0;
  const int r0 = c0 >> 4, e0 = (c0 & 15) * 8;
  const int r1 = c1 >> 4, e1 = (c1 & 15) * 8;
  const ushort_t* base = qkv + (size_t)(b*32)*N3;

  for (int d0 = 0; d0 < D2; d0 += 128){
    gld16(base + (size_t)r0*N3 + d0 + e0,        qs + (size_t)(w*64)*8);
    gld16(base + (size_t)r1*N3 + d0 + e1,        qs + (size_t)(256 + w*64)*8);
    gld16(base + (size_t)r0*N3 + D2 + d0 + e0,   ks + (size_t)(w*64)*8);
    gld16(base + (size_t)r1*N3 + D2 + d0 + e1,   ks + (size_t)(256 + w*64)*8);
    __syncthreads();
    #pragma unroll
    for (int kc = 0; kc < 4; ++kc){
      short8 a  = *(const short8*)(qs + (qh*16 + lr)*128 + kc*32 + lg*8);
      short8 bb = *(const short8*)(ks + (kh*16 + lr)*128 + kc*32 + lg*8);
      acc = __builtin_amdgcn_mfma_f32_16x16x32_bf16(a, bb, acc, 0, 0, 0);
    }
    __syncthreads();
  }
  const float rs = 0.022097086912079608f;  // 1/sqrt(2048)
  #pragma unroll
  for (int r = 0; r < 4; ++r){
    int qi = qh*16 + lg*4 + r, ki = kh*16 + lr;
    logits[(size_t)b*1024 + qi*32 + ki] = acc[r] * rs;
  }
}

// ---------------- final: softmax over qi (columns), P = v @ Wfc_r^T, out[b] = sum attn*P^T + bfc ----------------
__global__ __launch_bounds__(256) void k_final(const ushort_t* __restrict__ qkv,
                                               const ushort_t* __restrict__ wfcb,
                                               const float* __restrict__ logits,
                                               const float* __restrict__ bfc,
                                               float* __restrict__ out){
  __shared__ float attn[32*32];
  __shared__ alignas(16) ushort_t vs[32*128];
  __shared__ alignas(16) ushort_t ws[32*128];
  __shared__ float red[4];
  const int b = blockIdx.x;
  const int t = threadIdx.x, w = t >> 6, l = t & 63;
  const int kh = w >> 1, qh = w & 1;
  const int lr = l & 15, lg = l >> 4;

  // softmax over query axis: one column ki per thread (t<32)
  if (t < 32){
    int ki = t;
    const float* lg_b = logits + (size_t)b*1024;
    float mx = -1e30f;
    for (int qi = 0; qi < 32; ++qi) mx = fmaxf(mx, lg_b[qi*32 + ki]);
    float sm = 0.f;
    for (int qi = 0; qi < 32; ++qi){
      float e = expf(lg_b[qi*32 + ki] - mx);
      attn[qi*32 + ki] = e; sm += e;
    }
    float inv = 1.0f / sm;
    for (int qi = 0; qi < 32; ++qi) attn[qi*32 + ki] *= inv;
  }

  floatx4 acc = {0.f, 0.f, 0.f, 0.f};
  const int c0 = w*64 + l, c1 = 256 + c0;
  const int r0 = c0 >> 4, e0 = (c0 & 15) * 8;
  const int r1 = c1 >> 4, e1 = (c1 & 15) * 8;
  const ushort_t* vbase = qkv + (size_t)(b*32)*N3 + 2*D2;   // v block

  for (int d0 = 0; d0 < D2; d0 += 128){
    gld16(vbase + (size_t)r0*N3 + d0 + e0,  vs + (size_t)(w*64)*8);
    gld16(vbase + (size_t)r1*N3 + d0 + e1,  vs + (size_t)(256 + w*64)*8);
    gld16(wfcb + (size_t)r0*D2 + d0 + e0,   ws + (size_t)(w*64)*8);
    gld16(wfcb + (size_t)r1*D2 + d0 + e1,   ws + (size_t)(256 + w*64)*8);
    __syncthreads();
    #pragma unroll
    for (int kc = 0; kc < 4; ++kc){
      short8 a  = *(const short8*)(vs + (kh*16 + lr)*128 + kc*32 + lg*8);
      short8 bb = *(const short8*)(ws + (qh*16 + lr)*128 + kc*32 + lg*8);
      acc = __builtin_amdgcn_mfma_f32_16x16x32_bf16(a, bb, acc, 0, 0, 0);
    }
    __syncthreads();
  }

  // P[ki][qi] in acc; res = sum attn[qi][ki] * P[ki][qi]
  float sum = 0.f;
  #pragma unroll
  for (int r = 0; r < 4; ++r){
    int ki = kh*16 + lg*4 + r, qi = qh*16 + lr;
    sum += acc[r] * attn[qi*32 + ki];
  }
  #pragma unroll
  for (int off = 32; off > 0; off >>= 1) sum += __shfl_down(sum, off, 64);
  if (l == 0) red[w] = sum;
  __syncthreads();
  if (t == 0) out[b] = red[0] + red[1] + red[2] + red[3] + bfc[0];
}

// ---------------- host ----------------
extern "C" void kernel_launch(void* const* d_in, const int* in_sizes, int n_in,
                              void* d_out, int out_size, void* d_ws, size_t ws_size,
                              hipStream_t stream) {
  const float* x   = (const float*)d_in[0];
  const float* pe  = (const float*)d_in[1];
  const float* Wq  = (const float*)d_in[2];
  const float* bq  = (const float*)d_in[3];
  const float* Wk  = (const float*)d_in[4];
  const float* bk  = (const float*)d_in[5];
  const float* Wv  = (const float*)d_in[6];
  const float* bv  = (const float*)d_in[7];
  const float* Wfc = (const float*)d_in[8];
  const float* bfc = (const float*)d_in[9];
  float* out = (float*)d_out;
  (void)in_sizes; (void)n_in; (void)out_size; (void)ws_size;

  char* ws = (char*)d_ws;
  size_t off = 0;
  auto alloc = [&](size_t bytes) -> void* {
    void* p = ws + off;
    off += (bytes + 255) & ~(size_t)255;
    return p;
  };
  ushort_t* xb       = (ushort_t*)alloc((size_t)M_TOT * KDIM * 2);   //  64 MiB
  ushort_t* Wall     = (ushort_t*)alloc((size_t)N3 * KDIM * 2);      //  12 MiB
  float*    bias_all = (float*)   alloc((size_t)SSEQ * N3 * 4);      // 768 KiB
  ushort_t* wfcb     = (ushort_t*)alloc((size_t)SSEQ * D2 * 2);      // 128 KiB
  float*    logits   = (float*)   alloc((size_t)NBATCH * 1024 * 4);  //   4 MiB
  ushort_t* qkv      = (ushort_t*)alloc((size_t)M_TOT * N3 * 2);     // 384 MiB

  k_cast_x  <<<dim3(M_TOT*KDIM/8/256), dim3(256), 0, stream>>>(x, xb);
  k_cast_w  <<<dim3(N3*KDIM/8/256),    dim3(256), 0, stream>>>(Wq, Wk, Wv, Wall);
  k_cast_wfc<<<dim3(SSEQ*D2/8/256),    dim3(256), 0, stream>>>(Wfc, wfcb);
  k_bias    <<<dim3(N3/8),             dim3(256), 0, stream>>>(pe, Wq, bq, Wk, bk, Wv, bv, bias_all);
  k_gemm    <<<dim3(M_TOT/128, N3/128), dim3(256), 0, stream>>>(xb, Wall, bias_all, qkv);
  k_logits  <<<dim3(NBATCH),           dim3(256), 0, stream>>>(qkv, logits);
  k_final   <<<dim3(NBATCH),           dim3(256), 0, stream>>>(qkv, wfcb, logits, bfc, out);
}

// Round 2
// 819.839 us; speedup vs baseline: 1.1713x; 1.1713x over previous
//
#include <hip/hip_runtime.h>

typedef unsigned short ushort_t;
typedef __attribute__((ext_vector_type(8))) short short8;
typedef __attribute__((ext_vector_type(8))) unsigned short ushort8;
typedef __attribute__((ext_vector_type(4))) float floatx4;

#define M_TOT 32768   // B*S
#define KDIM  1024    // folded reduction dim (x part only)
#define N3    6144    // 3 * 2048 (q,k,v outputs)
#define D2    2048
#define NBATCH 1024
#define SSEQ   32

__device__ __forceinline__ ushort_t f2bf(float f){
  unsigned int u = __builtin_bit_cast(unsigned int, f);
  u += 0x7fffu + ((u >> 16) & 1u);           // RNE
  return (ushort_t)(u >> 16);
}

__device__ __forceinline__ void gld16(const void* g, void* l){
  __builtin_amdgcn_global_load_lds((__attribute__((address_space(1))) void*)g,
                                   (__attribute__((address_space(3))) void*)l,
                                   16, 0, 0);
}

__device__ __forceinline__ void barrier_raw(){
  asm volatile("" ::: "memory");
  __builtin_amdgcn_s_barrier();
  asm volatile("" ::: "memory");
}
#define WAIT_VM0   asm volatile("s_waitcnt vmcnt(0)" ::: "memory")
#define WAIT_LGKM0 asm volatile("s_waitcnt lgkmcnt(0)" ::: "memory")

// ---------------- prep kernels ----------------

__global__ void k_cast_x(const float* __restrict__ x, ushort_t* __restrict__ xb){
  size_t i = (size_t)blockIdx.x * 256 + threadIdx.x;   // one thread per 8 elems
  const float4* s = (const float4*)x;
  float4 a = s[2*i], b = s[2*i+1];
  ushort8 o;
  o[0]=f2bf(a.x); o[1]=f2bf(a.y); o[2]=f2bf(a.z); o[3]=f2bf(a.w);
  o[4]=f2bf(b.x); o[5]=f2bf(b.y); o[6]=f2bf(b.z); o[7]=f2bf(b.w);
  *(ushort8*)(xb + 8*i) = o;
}

// W_all[row=p*2048+n][j] = W_p[n][j] for j<1024  (left half of each weight row)
__global__ void k_cast_w(const float* __restrict__ Wq, const float* __restrict__ Wk,
                         const float* __restrict__ Wv, ushort_t* __restrict__ Wall){
  int i = blockIdx.x * 256 + threadIdx.x;
  int e = i * 8;
  int row = e >> 10, col = e & 1023;
  int p = row >> 11, n = row & 2047;
  const float* W = (p==0) ? Wq : (p==1) ? Wk : Wv;
  const float4* s = (const float4*)(W + (size_t)n*2048 + col);
  float4 a = s[0], b = s[1];
  ushort8 o;
  o[0]=f2bf(a.x); o[1]=f2bf(a.y); o[2]=f2bf(a.z); o[3]=f2bf(a.w);
  o[4]=f2bf(b.x); o[5]=f2bf(b.y); o[6]=f2bf(b.z); o[7]=f2bf(b.w);
  *(ushort8*)(Wall + (size_t)row*1024 + col) = o;
}

__global__ void k_cast_wfc(const float* __restrict__ Wfc, ushort_t* __restrict__ wfcb){
  int i = blockIdx.x * 256 + threadIdx.x;
  const float4* s = (const float4*)Wfc;
  float4 a = s[2*i], b = s[2*i+1];
  ushort8 o;
  o[0]=f2bf(a.x); o[1]=f2bf(a.y); o[2]=f2bf(a.z); o[3]=f2bf(a.w);
  o[4]=f2bf(b.x); o[5]=f2bf(b.y); o[6]=f2bf(b.z); o[7]=f2bf(b.w);
  *(ushort8*)(wfcb + 8*(size_t)i) = o;
}

// bias_all[s][p*2048+n] = b_p[n] + sum_j pe[s][j] * W_p[n][1024+j]   (fp32)
__global__ void k_bias(const float* __restrict__ pe,
                       const float* __restrict__ Wq, const float* __restrict__ bq,
                       const float* __restrict__ Wk, const float* __restrict__ bk,
                       const float* __restrict__ Wv, const float* __restrict__ bv,
                       float* __restrict__ bias_all){
  int t = threadIdx.x;
  int ni = t & 7, s = t >> 3;
  int col = blockIdx.x * 8 + ni;           // 0..6143
  int p = col >> 11, n = col & 2047;
  const float* W  = (p==0) ? Wq : (p==1) ? Wk : Wv;
  const float* bb = (p==0) ? bq : (p==1) ? bk : bv;
  const float4* w4 = (const float4*)(W + (size_t)n*2048 + 1024);
  const float4* p4 = (const float4*)(pe + (size_t)s*1024);
  float acc = 0.f;
  #pragma unroll 4
  for (int j = 0; j < 256; ++j){
    float4 w = w4[j], q = p4[j];
    acc += w.x*q.x + w.y*q.y + w.z*q.z + w.w*q.w;
  }
  bias_all[(size_t)s*N3 + col] = acc + bb[n];
}

// ---------------- QKV GEMM: 256x256 tile, BK=64, 8 waves (2x4), 4-phase pipeline ----------------
// qkv[m][n] = sum_k xb[m][k]*Wall[n][k] + bias_all[m%32][n]
// LDS: A/B 256x64 bf16 tiles, double-buffered = 128 KiB. T2 XOR swizzle (chunk ^= row&7).
__global__ __launch_bounds__(512, 2) void k_gemm(const ushort_t* __restrict__ xb,
                                                 const ushort_t* __restrict__ Wall,
                                                 const float* __restrict__ bias_all,
                                                 ushort_t* __restrict__ qkv){
  __shared__ alignas(16) ushort_t sA[2][256*64];
  __shared__ alignas(16) ushort_t sB[2][256*64];
  const int t = threadIdx.x, w = t >> 6, l = t & 63;
  const int wr = w >> 2, wc = w & 3;          // 2x4 wave grid -> wave owns 128x64 of C
  const int lr = l & 15, lg = l >> 4;
  const int m0 = blockIdx.x * 256;
  const int n0 = blockIdx.y * 256;

  // staging decode: round r covers chunks p = r*512 + t; row=p>>3, gchunk=(p&7)^(row&7)
  int soff[4];   // element offset within a 256-row x 1024-col operand panel (per k-tile base)
  #pragma unroll
  for (int r = 0; r < 4; ++r){
    int p = r*512 + t;
    int row = p >> 3;
    int c  = (p & 7) ^ (row & 7);
    soff[r] = row * KDIM + c * 8;
  }
  const ushort_t* gA = xb   + (size_t)m0 * KDIM;
  const ushort_t* gB = Wall + (size_t)n0 * KDIM;

  floatx4 acc[8][4] = {};

  auto STAGE = [&](int kt, int buf){
    const ushort_t* ga = gA + kt*64;
    const ushort_t* gb = gB + kt*64;
    #pragma unroll
    for (int r = 0; r < 4; ++r)
      gld16(ga + soff[r], &sA[buf][(r*512 + w*64)*8]);
    #pragma unroll
    for (int r = 0; r < 4; ++r)
      gld16(gb + soff[r], &sB[buf][(r*512 + w*64)*8]);
  };

  auto RDA = [&](int mh, int buf, short8* a){    // 4 m-frags x 2 k-steps
    #pragma unroll
    for (int mi = 0; mi < 4; ++mi){
      int row = wr*128 + mh*64 + mi*16 + lr;
      #pragma unroll
      for (int ks = 0; ks < 2; ++ks){
        int ch = (ks*4 + lg) ^ (row & 7);
        a[mi*2+ks] = *(const short8*)&sA[buf][row*64 + ch*8];
      }
    }
  };
  auto RDB = [&](int nh, int buf, short8* b){    // 2 n-frags x 2 k-steps
    #pragma unroll
    for (int ni = 0; ni < 2; ++ni){
      int row = wc*64 + (nh*2+ni)*16 + lr;
      #pragma unroll
      for (int ks = 0; ks < 2; ++ks){
        int ch = (ks*4 + lg) ^ (row & 7);
        b[ni*2+ks] = *(const short8*)&sB[buf][row*64 + ch*8];
      }
    }
  };
  auto MM = [&](int mh, int nh, const short8* a, const short8* b){  // 16 MFMA
    #pragma unroll
    for (int mi = 0; mi < 4; ++mi)
      #pragma unroll
      for (int ni = 0; ni < 2; ++ni)
        #pragma unroll
        for (int ks = 0; ks < 2; ++ks)
          acc[mh*4+mi][nh*2+ni] = __builtin_amdgcn_mfma_f32_16x16x32_bf16(
              a[mi*2+ks], b[ni*2+ks], acc[mh*4+mi][nh*2+ni], 0, 0, 0);
  };

  // prologue: stage tile 0, drain, barrier
  STAGE(0, 0);
  WAIT_VM0;
  barrier_raw();

  const int NT = KDIM / 64;   // 16
  for (int kt = 0; kt < NT; ++kt){
    const int cur = kt & 1;
    const bool pre = (kt + 1) < NT;
    short8 a[8], b0[4], b1[4];

    // P0: reads A-m0(8) + B-n0(4); stage ALL of next tile (8 gld16, ~3 phases of cover)
    RDA(0, cur, a);
    RDB(0, cur, b0);
    if (pre) STAGE(kt+1, cur^1);
    barrier_raw();
    WAIT_LGKM0; __builtin_amdgcn_sched_barrier(0);
    __builtin_amdgcn_s_setprio(1); MM(0, 0, a, b0); __builtin_amdgcn_s_setprio(0);
    barrier_raw();

    // P1: reads B-n1(4)
    RDB(1, cur, b1);
    barrier_raw();
    WAIT_LGKM0; __builtin_amdgcn_sched_barrier(0);
    __builtin_amdgcn_s_setprio(1); MM(0, 1, a, b1); __builtin_amdgcn_s_setprio(0);
    barrier_raw();

    // P2: reads A-m1(8)
    RDA(1, cur, a);
    barrier_raw();
    WAIT_LGKM0; __builtin_amdgcn_sched_barrier(0);
    __builtin_amdgcn_s_setprio(1); MM(1, 1, a, b1); __builtin_amdgcn_s_setprio(0);
    barrier_raw();

    // P3: no new reads; MFMA (m1,n0); wait next tile's stages (issued at P0) before swap
    WAIT_LGKM0; __builtin_amdgcn_sched_barrier(0);
    __builtin_amdgcn_s_setprio(1); MM(1, 0, a, b0); __builtin_amdgcn_s_setprio(0);
    if (pre) WAIT_VM0;
    barrier_raw();
  }

  // epilogue: C/D layout col=lr, row=lg*4+r
  #pragma unroll
  for (int mf = 0; mf < 8; ++mf){
    #pragma unroll
    for (int nf = 0; nf < 4; ++nf){
      #pragma unroll
      for (int r = 0; r < 4; ++r){
        int row = m0 + wr*128 + mf*16 + lg*4 + r;
        int col = n0 + wc*64 + nf*16 + lr;
        float v = acc[mf][nf][r] + bias_all[(size_t)(row & 31)*N3 + col];
        qkv[(size_t)row*N3 + col] = f2bf(v);
      }
    }
  }
}

// ---------------- fused attention tail: logits -> softmax(dim=q) -> P=v@Wfc^T -> out ----------------
// one block per batch; 256 threads; swizzled LDS staging (chunk ^= row&15 within 256B rows)
__global__ __launch_bounds__(256) void k_attn(const ushort_t* __restrict__ qkv,
                                              const ushort_t* __restrict__ wfcb,
                                              const float* __restrict__ bfc,
                                              float* __restrict__ out){
  __shared__ float attn[32*32];
  __shared__ alignas(16) ushort_t s0[32*128];   // q, then v
  __shared__ alignas(16) ushort_t s1[32*128];   // k, then wfc
  __shared__ float red[4];
  const int b = blockIdx.x;
  const int t = threadIdx.x, w = t >> 6, l = t & 63;
  const int qh = w >> 1, kh = w & 1;
  const int lr = l & 15, lg = l >> 4;

  // staging decode: round r covers chunks p = r*256 + t; row=p>>4, gcol=((p&15)^(row&15))*8
  int srow[2], scol[2];
  #pragma unroll
  for (int r = 0; r < 2; ++r){
    int p = r*256 + t;
    srow[r] = p >> 4;
    scol[r] = ((p & 15) ^ (srow[r] & 15)) * 8;
  }
  const ushort_t* base = qkv + (size_t)(b*32)*N3;

  // ---- logits = q k^T / sqrt(2048) ----
  floatx4 aq = {0.f, 0.f, 0.f, 0.f};
  for (int d0 = 0; d0 < D2; d0 += 128){
    #pragma unroll
    for (int r = 0; r < 2; ++r){
      gld16(base + (size_t)srow[r]*N3 + d0 + scol[r],      s0 + (size_t)(r*256 + w*64)*8);
      gld16(base + (size_t)srow[r]*N3 + D2 + d0 + scol[r], s1 + (size_t)(r*256 + w*64)*8);
    }
    __syncthreads();
    #pragma unroll
    for (int kc = 0; kc < 4; ++kc){
      int rowa = qh*16 + lr, rowb = kh*16 + lr;
      short8 va = *(const short8*)(s0 + rowa*128 + (((kc*4+lg) ^ (rowa & 15))*8));
      short8 vb = *(const short8*)(s1 + rowb*128 + (((kc*4+lg) ^ (rowb & 15))*8));
      aq = __builtin_amdgcn_mfma_f32_16x16x32_bf16(va, vb, aq, 0, 0, 0);
    }
    __syncthreads();
  }
  const float rs = 0.022097086912079608f;  // 1/sqrt(2048)
  #pragma unroll
  for (int r = 0; r < 4; ++r){
    int qi = qh*16 + lg*4 + r, ki = kh*16 + lr;
    attn[qi*32 + ki] = aq[r] * rs;
  }
  __syncthreads();

  // ---- softmax over query axis (column-wise), t<32 handles column ki=t ----
  if (t < 32){
    int ki = t;
    float mx = -1e30f;
    #pragma unroll 4
    for (int qi = 0; qi < 32; ++qi) mx = fmaxf(mx, attn[qi*32 + ki]);
    float sm = 0.f;
    #pragma unroll 4
    for (int qi = 0; qi < 32; ++qi){
      float e = __expf(attn[qi*32 + ki] - mx);
      attn[qi*32 + ki] = e; sm += e;
    }
    float inv = 1.0f / sm;
    #pragma unroll 4
    for (int qi = 0; qi < 32; ++qi) attn[qi*32 + ki] *= inv;
  }
  __syncthreads();

  // ---- P[ki][qi] = sum_d v[ki,d]*wfc[qi,d]; out[b] = sum attn[qi][ki]*P[ki][qi] + bfc ----
  floatx4 ap = {0.f, 0.f, 0.f, 0.f};
  const ushort_t* vbase = base + 2*D2;
  for (int d0 = 0; d0 < D2; d0 += 128){
    #pragma unroll
    for (int r = 0; r < 2; ++r){
      gld16(vbase + (size_t)srow[r]*N3 + d0 + scol[r], s0 + (size_t)(r*256 + w*64)*8);
      gld16(wfcb  + (size_t)srow[r]*D2 + d0 + scol[r], s1 + (size_t)(r*256 + w*64)*8);
    }
    __syncthreads();
    #pragma unroll
    for (int kc = 0; kc < 4; ++kc){
      int rowa = kh*16 + lr, rowb = qh*16 + lr;   // A = v rows (ki), B = wfc rows (qi)
      short8 va = *(const short8*)(s0 + rowa*128 + (((kc*4+lg) ^ (rowa & 15))*8));
      short8 vb = *(const short8*)(s1 + rowb*128 + (((kc*4+lg) ^ (rowb & 15))*8));
      ap = __builtin_amdgcn_mfma_f32_16x16x32_bf16(va, vb, ap, 0, 0, 0);
    }
    __syncthreads();
  }

  float sum = 0.f;
  #pragma unroll
  for (int r = 0; r < 4; ++r){
    int ki = kh*16 + lg*4 + r, qi = qh*16 + lr;
    sum += ap[r] * attn[qi*32 + ki];
  }
  #pragma unroll
  for (int off = 32; off > 0; off >>= 1) sum += __shfl_down(sum, off, 64);
  if (l == 0) red[w] = sum;
  __syncthreads();
  if (t == 0) out[b] = red[0] + red[1] + red[2] + red[3] + bfc[0];
}

// ---------------- host ----------------
extern "C" void kernel_launch(void* const* d_in, const int* in_sizes, int n_in,
                              void* d_out, int out_size, void* d_ws, size_t ws_size,
                              hipStream_t stream) {
  const float* x   = (const float*)d_in[0];
  const float* pe  = (const float*)d_in[1];
  const float* Wq  = (const float*)d_in[2];
  const float* bq  = (const float*)d_in[3];
  const float* Wk  = (const float*)d_in[4];
  const float* bk  = (const float*)d_in[5];
  const float* Wv  = (const float*)d_in[6];
  const float* bv  = (const float*)d_in[7];
  const float* Wfc = (const float*)d_in[8];
  const float* bfc = (const float*)d_in[9];
  float* out = (float*)d_out;
  (void)in_sizes; (void)n_in; (void)out_size; (void)ws_size;

  char* ws = (char*)d_ws;
  size_t off = 0;
  auto alloc = [&](size_t bytes) -> void* {
    void* p = ws + off;
    off += (bytes + 255) & ~(size_t)255;
    return p;
  };
  ushort_t* xb       = (ushort_t*)alloc((size_t)M_TOT * KDIM * 2);   //  64 MiB
  ushort_t* Wall     = (ushort_t*)alloc((size_t)N3 * KDIM * 2);      //  12 MiB
  float*    bias_all = (float*)   alloc((size_t)SSEQ * N3 * 4);      // 768 KiB
  ushort_t* wfcb     = (ushort_t*)alloc((size_t)SSEQ * D2 * 2);      // 128 KiB
  ushort_t* qkv      = (ushort_t*)alloc((size_t)M_TOT * N3 * 2);     // 384 MiB

  k_cast_x  <<<dim3(M_TOT*KDIM/8/256), dim3(256), 0, stream>>>(x, xb);
  k_cast_w  <<<dim3(N3*KDIM/8/256),    dim3(256), 0, stream>>>(Wq, Wk, Wv, Wall);
  k_cast_wfc<<<dim3(SSEQ*D2/8/256),    dim3(256), 0, stream>>>(Wfc, wfcb);
  k_bias    <<<dim3(N3/8),             dim3(256), 0, stream>>>(pe, Wq, bq, Wk, bk, Wv, bv, bias_all);
  k_gemm    <<<dim3(M_TOT/256, N3/256), dim3(512), 0, stream>>>(xb, Wall, bias_all, qkv);
  k_attn    <<<dim3(NBATCH),           dim3(256), 0, stream>>>(qkv, wfcb, bfc, out);
}